// Round 13
// baseline (435.311 us; speedup 1.0000x reference)
//
#include <hip/hip_runtime.h>

typedef float f4 __attribute__((ext_vector_type(4)));

// Problem constants
constexpr int Bn = 16;
constexpr int Sn = 8192;
constexpr int Dn = 256;             // D_MODEL = K_CH = OUT = 256
constexpr float kScale = 0.0625f;   // 1/sqrt(256)
constexpr int NCHUNK = 64;          // chunks (producer blocks) per batch
constexpr int NBLK   = Bn * NCHUNK; // 1024 = 256 CU x 4 blocks -> co-resident

// Workspace layout (float offsets)
constexpr int R_OFF    = 0;                     // r[B][D] = Wk @ q
constexpr int C_OFF    = R_OFF + Bn * Dn;       // c[B]
constexpr int M_OFF    = C_OFF + 64;            // chunk max   [B][NCHUNK]
constexpr int SUM_OFF  = M_OFF + Bn * NCHUNK;   // chunk expsum[B][NCHUNK]
constexpr int PART_OFF = SUM_OFF + Bn * NCHUNK; // partials    [B][NCHUNK][D]
constexpr int DONE_OFF = PART_OFF + Bn * NCHUNK * Dn;  // int done[B]

// ---------------------------------------------------------------------------
// Wave-wide float sum on the VALU pipe (DPP) — zero DS ops.
template <int CTRL>
__device__ __forceinline__ float dpp_term(float x) {
  return __builtin_bit_cast(float,
      __builtin_amdgcn_update_dpp(0, __builtin_bit_cast(int, x),
                                  CTRL, 0xf, 0xf, true));
}
__device__ __forceinline__ float wave_sum_dpp(float x) {
  x += dpp_term<0x111>(x);   // row_shr:1
  x += dpp_term<0x112>(x);   // row_shr:2
  x += dpp_term<0x114>(x);   // row_shr:4
  x += dpp_term<0x118>(x);   // row_shr:8
  x += dpp_term<0x142>(x);   // row_bcast:15
  x += dpp_term<0x143>(x);   // row_bcast:31
  return __builtin_bit_cast(float,
      __builtin_amdgcn_readlane(__builtin_bit_cast(int, x), 63));
}

// ---------------------------------------------------------------------------
// K1: per-batch tiny GEMVs: q = query@Wq + bq ; r = Wk@q ; c = q.bk
// (unchanged)
__global__ __launch_bounds__(256) void k_qrc(
    const float* __restrict__ query, const float* __restrict__ Wq,
    const float* __restrict__ bq, const float* __restrict__ Wk,
    const float* __restrict__ bk, float* __restrict__ ws) {
  int b = blockIdx.x, t = threadIdx.x;
  __shared__ float qs[Dn];
  __shared__ float qh[Dn];
  __shared__ float red[256];
  qs[t] = query[b * Dn + t];
  __syncthreads();
  float acc = bq[t];
  #pragma unroll 32
  for (int d = 0; d < Dn; ++d) acc += qs[d] * Wq[d * Dn + t];  // coalesced over t
  qh[t] = acc;
  __syncthreads();
  float racc = 0.f;
  const f4* wkrow = (const f4*)(Wk + (size_t)t * Dn);
  const f4* qh4 = (const f4*)qh;
  #pragma unroll 16
  for (int o4 = 0; o4 < Dn / 4; ++o4) {
    f4 wv = wkrow[o4];
    f4 qv = qh4[o4];
    racc += wv.x * qv.x + wv.y * qv.y + wv.z * qv.z + wv.w * qv.w;
  }
  ws[R_OFF + b * Dn + t] = racc;
  red[t] = qh[t] * bk[t];
  __syncthreads();
  for (int off = 128; off; off >>= 1) {
    if (t < off) red[t] += red[t + off];
    __syncthreads();
  }
  if (t == 0) ws[C_OFF + b] = red[0];
}

// ---------------------------------------------------------------------------
// K2 (mega): produce partial for chunk (b,c), signal done[b], wait for the
// batch, then combine + nt-write this block's 128-row output slice.
// grid = 1024 blocks of 256 threads; __launch_bounds__(256,4) + 6.9KB LDS
// guarantee 4 blocks/CU co-residency -> the flag wait cannot deadlock.
__global__ __launch_bounds__(256, 4) void k_mega(
    const float* __restrict__ key, const float* __restrict__ value,
    const float* __restrict__ Wv, const float* __restrict__ bv,
    float* __restrict__ ws, float* __restrict__ out) {
  int blk = blockIdx.x;
  int b = blk >> 6;         // / NCHUNK
  int c = blk & 63;
  int t = threadIdx.x, lane = t & 63, wv = t >> 6;
  int cw = c * 4 + wv;      // 0..255: wave's position in the 256-row front
  int* done = (int*)(ws + DONE_OFF);

  __shared__ float wm[4], wsum[4];
  __shared__ f4 wva[4][64];   // per-wave vacc (4 KB)
  __shared__ float msh[NCHUNK], ssh[NCHUNK], e[NCHUNK];
  __shared__ float ush[Dn], ctx[Dn];

  // ---------------- producer: online softmax over 128 rows -----------------
  f4 rv = ((const f4*)(ws + R_OFF + b * Dn))[lane] * kScale;
  float cb = ws[C_OFF + b] * kScale;
  const f4* kp = (const f4*)(key + (size_t)b * Sn * Dn);
  const f4* vp = (const f4*)(value + (size_t)b * Sn * Dn);

  float m = -1e30f, sum = 0.f;
  f4 vacc = {0.f, 0.f, 0.f, 0.f};

  f4 kv = kp[(size_t)cw * 64 + lane];
  f4 vv = vp[(size_t)cw * 64 + lane];
  #pragma unroll
  for (int i = 0; i < 32; ++i) {          // 32 rows per wave, 256 apart
    f4 kn, vn;
    if (i < 31) {                         // depth-1 prefetch
      size_t sn = (size_t)(i + 1) * 256 + cw;
      kn = kp[sn * 64 + lane];
      vn = vp[sn * 64 + lane];
    }
    float pd = kv.x * rv.x + kv.y * rv.y + kv.z * rv.z + kv.w * rv.w;
    float s = wave_sum_dpp(pd) + cb;      // uniform in all lanes
    if (s > m) {                          // wave-uniform, rare
      float sc = __expf(m - s);
      sum *= sc;
      vacc *= sc;
      m = s;
    }
    float w = __expf(s - m);
    sum += w;
    vacc += w * vv;
    kv = kn; vv = vn;
  }

  if (lane == 0) { wm[wv] = m; wsum[wv] = sum; }
  wva[wv][lane] = vacc;
  __syncthreads();

  float gm = fmaxf(fmaxf(wm[0], wm[1]), fmaxf(wm[2], wm[3]));
  float e0 = __expf(wm[0] - gm), e1 = __expf(wm[1] - gm);
  float e2 = __expf(wm[2] - gm), e3 = __expf(wm[3] - gm);
  const float* v0 = (const float*)&wva[0][0];
  const float* v1 = (const float*)&wva[1][0];
  const float* v2 = (const float*)&wva[2][0];
  const float* v3 = (const float*)&wva[3][0];
  float part = v0[t] * e0 + v1[t] * e1 + v2[t] * e2 + v3[t] * e3;
  ws[PART_OFF + ((size_t)b * NCHUNK + c) * Dn + t] = part;
  if (t == 0) {
    ws[M_OFF + b * NCHUNK + c] = gm;
    ws[SUM_OFF + b * NCHUNK + c] =
        wsum[0] * e0 + wsum[1] * e1 + wsum[2] * e2 + wsum[3] * e3;
  }

  // ---------------- signal & wait (device-scope, G16) -----------------------
  __threadfence();            // release: partials visible device-wide
  __syncthreads();            // all threads' fences done
  if (t == 0) {
    __atomic_fetch_add(done + b, 1, __ATOMIC_RELEASE);
    while (__hip_atomic_load(done + b, __ATOMIC_ACQUIRE,
                             __HIP_MEMORY_SCOPE_AGENT) < NCHUNK)
      __builtin_amdgcn_s_sleep(8);
    __threadfence();          // acquire: invalidate stale L1/L2 lines
  }
  __syncthreads();

  // ---------------- writer: LSE combine -> ctx -> nt-write slice ------------
  if (t < NCHUNK)           msh[t] = ws[M_OFF + b * NCHUNK + t];
  else if (t < 2 * NCHUNK)  ssh[t - NCHUNK] = ws[SUM_OFF + b * NCHUNK + (t - NCHUNK)];
  __syncthreads();
  float gmb = -1e30f;
  #pragma unroll 16
  for (int k = 0; k < NCHUNK; ++k) gmb = fmaxf(gmb, msh[k]);
  if (t < NCHUNK) e[t] = __expf(msh[t] - gmb);
  __syncthreads();
  float denom = 0.f;
  #pragma unroll 16
  for (int k = 0; k < NCHUNK; ++k) denom += ssh[k] * e[k];
  float u = 0.f;
  #pragma unroll 16
  for (int k = 0; k < NCHUNK; ++k)
    u += ws[PART_OFF + ((size_t)b * NCHUNK + k) * Dn + t] * e[k];  // coalesced
  ush[t] = u / denom;
  __syncthreads();
  float acc = bv[t];
  #pragma unroll 16
  for (int o = 0; o < Dn; ++o) acc += ush[o] * Wv[o * Dn + t];  // coalesced
  ctx[t] = acc;
  __syncthreads();

  f4 val = ((const f4*)ctx)[lane];
  f4* op = (f4*)(out + (size_t)b * Sn * Dn);
  #pragma unroll 8
  for (int i = 0; i < 32; ++i) {
    size_t s = (size_t)i * 256 + cw;      // interleaved write front
    __builtin_nontemporal_store(val, &op[s * 64 + lane]);
  }
}

// ---------------------------------------------------------------------------
extern "C" void kernel_launch(void* const* d_in, const int* in_sizes, int n_in,
                              void* d_out, int out_size, void* d_ws, size_t ws_size,
                              hipStream_t stream) {
  const float* query = (const float*)d_in[0];
  const float* key   = (const float*)d_in[1];
  const float* value = (const float*)d_in[2];
  const float* Wq    = (const float*)d_in[3];
  const float* bq    = (const float*)d_in[4];
  const float* Wk    = (const float*)d_in[5];
  const float* bk    = (const float*)d_in[6];
  const float* Wv    = (const float*)d_in[7];
  const float* bv    = (const float*)d_in[8];
  float* out = (float*)d_out;
  float* ws  = (float*)d_ws;

  // Zero the done-flags every launch (graph-replayed too).
  hipMemsetAsync(ws + DONE_OFF, 0, Bn * sizeof(int), stream);
  hipLaunchKernelGGL(k_qrc,  dim3(Bn),   dim3(256), 0, stream,
                     query, Wq, bq, Wk, bk, ws);
  hipLaunchKernelGGL(k_mega, dim3(NBLK), dim3(256), 0, stream,
                     key, value, Wv, bv, ws, out);
}